// Round 1
// baseline (128.105 us; speedup 1.0000x reference)
//
#include <hip/hip_runtime.h>
#include <hip/hip_bf16.h>

// CARNN: 9-step RNN (D=64) + projection to 300 actions, BATCH=65536.
// R6: LDS-instruction-throughput fix. Wave geometry 16x32 rows/feats ->
// 32x32 (two 16-row subtiles share one set of B-fragments), halving the
// per-CU weight ds_read count (256->128/step). 512-thr blocks, grid 512,
// 2 blocks/CU, 4 waves/SIMD, VGPR cap 128 (was 64 -> spill risk gone).
// Step 0 skips H reads + H*W MFMAs (H0 == 0, bit-identical). Projection
// reads out_w fragments directly from global (40 KB, L2-resident, shared
// by every wave) -> no projection staging, no projection barriers.

#define SEQ     9
#define DMODEL  64
#define ANUM    300
#define RPB     128   // rows per block
#define LSTR    72    // H row stride (bf16 elems)

// ws layout (bf16 element offsets) -- unchanged, prepack identical
#define WS_MW   0        // 9*8192: per step [kind(M=0,W=1)][nt][kb][lane][8]
#define WS_OW   73728    // 5*4096: [cc][nt][kb][lane][8]
#define WS_EMB  94208    // 301*64 bf16 emb table
#define WS_END  113472
#define WS_BSUM_BYTES (WS_END * 2)

typedef __attribute__((ext_vector_type(8))) short  bf16x8;
typedef __attribute__((ext_vector_type(4))) float  f32x4;

__device__ __forceinline__ unsigned short f2b(float f) {
    union { float f; unsigned int u; } x; x.f = f;
    unsigned int r = x.u + 0x7FFFu + ((x.u >> 16) & 1u);
    return (unsigned short)(r >> 16);
}

__device__ __forceinline__ float sigmoid_fast(float v) {
    return __builtin_amdgcn_rcpf(1.f + __expf(-v));
}

// async global->LDS, 16 B per lane; lds base must be wave-uniform
__device__ __forceinline__ void async16(const unsigned short* g, unsigned short* l) {
    __builtin_amdgcn_global_load_lds(
        (const __attribute__((address_space(1))) unsigned int*)g,
        (__attribute__((address_space(3))) unsigned int*)l, 16, 0, 0);
}

// ---------------- pre-pass: convert + pack (unchanged) ----------------
#define PP_TOTAL (73728 + 20480 + 19264 + 576)

__global__ void prepack(const float* __restrict__ Mw, const float* __restrict__ Ww,
                        const float* __restrict__ outw, const float* __restrict__ emb,
                        const float* __restrict__ Mb, const float* __restrict__ Wb,
                        unsigned short* __restrict__ wsb, float* __restrict__ bsum)
{
    int t = blockIdx.x * 256 + threadIdx.x;
    if (t < 73728) {                       // M+W, step-major 16KB blocks
        int s    = t >> 13;
        int r    = t & 8191;
        int kind = r >> 12;
        int f    = r & 4095;
        int nt   = f >> 10;
        int kb   = (f >> 9) & 1;
        int lane = (f >> 3) & 63;
        int j    = f & 7;
        int nr   = nt * 16 + (lane & 15);
        int k    = kb * 32 + ((lane >> 4) << 3) + j;
        const float* src = kind ? Ww : Mw;
        wsb[WS_MW + t] = f2b(src[(s * DMODEL + nr) * DMODEL + k]);
        return;
    }
    t -= 73728;
    if (t < 20480) {                       // outw fragments
        int j    = t & 7;
        int lane = (t >> 3) & 63;
        int kb   = (t >> 9) & 1;
        int nt   = (t >> 10) & 3;
        int cc   = t >> 12;
        int col  = cc * 64 + nt * 16 + (lane & 15);
        int k    = kb * 32 + ((lane >> 4) << 3) + j;
        float v  = (col < ANUM) ? outw[col * DMODEL + k] : 0.f;
        wsb[WS_OW + t] = f2b(v);
        return;
    }
    t -= 20480;
    if (t < 19264) { wsb[WS_EMB + t] = f2b(emb[t]); return; }
    t -= 19264;
    if (t < 576)   { bsum[t] = Mb[t] + Wb[t]; }
}

// ---------------- main ----------------
__global__ __launch_bounds__(512, 4)
void carnn_main(const int* __restrict__ acts,
                const unsigned short* __restrict__ wsb,
                const float* __restrict__ bsum,
                const float* __restrict__ outb,
                float* __restrict__ out)
{
    __shared__ __align__(16) unsigned short Wf[2][8192];        // 2 x 16 KB weights
    __shared__ __align__(16) unsigned short Hl[2][RPB * LSTR];  // 2 x 18 KB hidden

    const int tid  = threadIdx.x;
    const int lane = tid & 63;
    const int wv   = tid >> 6;         // 0..7
    const int rg   = wv >> 1;          // 0..3: 32-row group
    const int half = wv & 1;           // nt pair: {0,1} or {2,3}
    const int lrow = lane & 15;
    const int quad = lane >> 4;

    const int rb0   = rg * 32 + lrow;              // subtile-0 row in block
    const int rb1   = rb0 + 16;                    // subtile-1 row in block
    const int brow0 = blockIdx.x * RPB + rb0;
    const int brow1 = brow0 + 16;
    const int hoff0 = rb0 * LSTR + quad * 8;
    const int hoff1 = rb1 * LSTR + quad * 8;

    // stage step-0 weights (16 KB = 2 x 16B per thread)
    async16(wsb + WS_MW + tid * 8,        &Wf[0][wv * 512]);
    async16(wsb + WS_MW + 4096 + tid * 8, &Wf[0][4096 + wv * 512]);

    const unsigned short* Eb = wsb + WS_EMB;
    int id0 = acts[brow0 * SEQ];       // step-0 action ids (2 subtiles)
    int id1 = acts[brow1 * SEQ];

    __syncthreads();                   // drains vmcnt -> stage-0 complete

    #pragma unroll
    for (int s = 0; s < SEQ; ++s) {
        const int rbuf = s & 1, wbuf = rbuf ^ 1;

        // X fragments (direct gather from bf16 emb table), both subtiles
        const bf16x8* e0 = (const bf16x8*)(Eb + id0 * DMODEL);
        const bf16x8* e1 = (const bf16x8*)(Eb + id1 * DMODEL);
        bf16x8 ax00 = e0[quad], ax01 = e0[4 + quad];
        bf16x8 ax10 = e1[quad], ax11 = e1[4 + quad];

        // prefetch next action ids + next weight block
        if (s + 1 < SEQ) {
            id0 = acts[brow0 * SEQ + s + 1];
            id1 = acts[brow1 * SEQ + s + 1];
            async16(wsb + WS_MW + (s + 1) * 8192 + tid * 8,        &Wf[wbuf][wv * 512]);
            async16(wsb + WS_MW + (s + 1) * 8192 + 4096 + tid * 8, &Wf[wbuf][4096 + wv * 512]);
        }

        // H fragments (previous step) -- skipped at s==0 (H0 == 0)
        bf16x8 ah00, ah01, ah10, ah11;
        if (s > 0) {
            ah00 = *(const bf16x8*)&Hl[rbuf][hoff0];
            ah01 = *(const bf16x8*)&Hl[rbuf][hoff0 + 32];
            ah10 = *(const bf16x8*)&Hl[rbuf][hoff1];
            ah11 = *(const bf16x8*)&Hl[rbuf][hoff1 + 32];
        }

        #pragma unroll
        for (int ntl = 0; ntl < 2; ++ntl) {
            const int nt = half * 2 + ntl;
            const unsigned short* Mf = &Wf[rbuf][nt * 1024 + lane * 8];
            bf16x8 bm0 = *(const bf16x8*)Mf;
            bf16x8 bm1 = *(const bf16x8*)(Mf + 512);

            f32x4 a0 = {0.f, 0.f, 0.f, 0.f};
            f32x4 a1 = {0.f, 0.f, 0.f, 0.f};
            a0 = __builtin_amdgcn_mfma_f32_16x16x32_bf16(ax00, bm0, a0, 0, 0, 0);
            a0 = __builtin_amdgcn_mfma_f32_16x16x32_bf16(ax01, bm1, a0, 0, 0, 0);
            a1 = __builtin_amdgcn_mfma_f32_16x16x32_bf16(ax10, bm0, a1, 0, 0, 0);
            a1 = __builtin_amdgcn_mfma_f32_16x16x32_bf16(ax11, bm1, a1, 0, 0, 0);
            if (s > 0) {
                const unsigned short* Wp = &Wf[rbuf][4096 + nt * 1024 + lane * 8];
                bf16x8 bw0 = *(const bf16x8*)Wp;
                bf16x8 bw1 = *(const bf16x8*)(Wp + 512);
                a0 = __builtin_amdgcn_mfma_f32_16x16x32_bf16(ah00, bw0, a0, 0, 0, 0);
                a0 = __builtin_amdgcn_mfma_f32_16x16x32_bf16(ah01, bw1, a0, 0, 0, 0);
                a1 = __builtin_amdgcn_mfma_f32_16x16x32_bf16(ah10, bw0, a1, 0, 0, 0);
                a1 = __builtin_amdgcn_mfma_f32_16x16x32_bf16(ah11, bw1, a1, 0, 0, 0);
            }

            const int col   = nt * 16 + lrow;
            const float bias = bsum[s * DMODEL + col];
            const int wr0 = (rg * 32 + quad * 4) * LSTR + col;
            const int wr1 = wr0 + 16 * LSTR;
            #pragma unroll
            for (int r = 0; r < 4; ++r) {
                Hl[wbuf][wr0 + r * LSTR] = f2b(sigmoid_fast(a0[r] + bias));
                Hl[wbuf][wr1 + r * LSTR] = f2b(sigmoid_fast(a1[r] + bias));
            }
        }
        __syncthreads();   // publishes H(s+1) AND completes weight prefetch
    }

    // ---- projection: final H in Hl[1]; out_w frags straight from global ----
    bf16x8 ah00 = *(const bf16x8*)&Hl[1][hoff0];
    bf16x8 ah01 = *(const bf16x8*)&Hl[1][hoff0 + 32];
    bf16x8 ah10 = *(const bf16x8*)&Hl[1][hoff1];
    bf16x8 ah11 = *(const bf16x8*)&Hl[1][hoff1 + 32];

    const unsigned short* OWg = wsb + WS_OW;
    const int rowb0 = blockIdx.x * RPB + rg * 32 + quad * 4;
    const int rowb1 = rowb0 + 16;

    #pragma unroll
    for (int cc = 0; cc < 5; ++cc) {
        #pragma unroll
        for (int ntl = 0; ntl < 2; ++ntl) {
            const int nt = half * 2 + ntl;
            const unsigned short* Of = OWg + cc * 4096 + nt * 1024 + lane * 8;
            bf16x8 b0 = *(const bf16x8*)Of;
            bf16x8 b1 = *(const bf16x8*)(Of + 512);

            f32x4 a0 = {0.f, 0.f, 0.f, 0.f};
            f32x4 a1 = {0.f, 0.f, 0.f, 0.f};
            a0 = __builtin_amdgcn_mfma_f32_16x16x32_bf16(ah00, b0, a0, 0, 0, 0);
            a0 = __builtin_amdgcn_mfma_f32_16x16x32_bf16(ah01, b1, a0, 0, 0, 0);
            a1 = __builtin_amdgcn_mfma_f32_16x16x32_bf16(ah10, b0, a1, 0, 0, 0);
            a1 = __builtin_amdgcn_mfma_f32_16x16x32_bf16(ah11, b1, a1, 0, 0, 0);

            const int col = cc * 64 + nt * 16 + lrow;
            if (col < ANUM) {
                const float bias = outb[col];
                #pragma unroll
                for (int r = 0; r < 4; ++r) {
                    out[(rowb0 + r) * ANUM + col] = a0[r] + bias;
                    out[(rowb1 + r) * ANUM + col] = a1[r] + bias;
                }
            }
        }
    }
}

extern "C" void kernel_launch(void* const* d_in, const int* in_sizes, int n_in,
                              void* d_out, int out_size, void* d_ws, size_t ws_size,
                              hipStream_t stream) {
    const int*   acts = (const int*)  d_in[0];
    const float* emb  = (const float*)d_in[1];
    const float* Mw   = (const float*)d_in[2];
    const float* Mb   = (const float*)d_in[3];
    const float* Ww   = (const float*)d_in[4];
    const float* Wb   = (const float*)d_in[5];
    const float* outw = (const float*)d_in[6];
    const float* outb = (const float*)d_in[7];
    float* out = (float*)d_out;
    (void)in_sizes; (void)n_in; (void)ws_size; (void)out_size;

    unsigned short* wsb = (unsigned short*)d_ws;
    float* bsum = (float*)((char*)d_ws + WS_BSUM_BYTES);

    prepack<<<(PP_TOTAL + 255) / 256, 256, 0, stream>>>(Mw, Ww, outw, emb, Mb, Wb, wsb, bsum);
    carnn_main<<<65536 / RPB, 512, 0, stream>>>(acts, wsb, bsum, outb, out);
}

// Round 2
// 120.450 us; speedup vs baseline: 1.0636x; 1.0636x over previous
//
#include <hip/hip_runtime.h>
#include <hip/hip_bf16.h>

// CARNN: 9-step RNN (D=64) + projection to 300 actions, BATCH=65536.
// R7: barrier-free RNN. Each wave owns 16 rows x all 64 feats -> H stays
// wave-private (2KB XOR-swizzled LDS scratch, lgkmcnt-only ordering).
// Swapped MFMA operands (A=weights, B=x/h) -> D[out,batch]: packed b64 H
// writes, f32x4 bias init, f32x4 projection stores. All step-0..7 weights
// (120KB) + bsum staged once, ONE __syncthreads total; s8 weights + out_w
// read from L2. 256 blocks x 1024 thr, 1 block/CU, 16 waves free-running.

#define SEQ     9
#define DMODEL  64
#define ANUM    300

// ws layout (bf16 element offsets) -- unchanged, prepack identical
#define WS_MW   0        // 9*8192: per step [kind(M=0,W=1)][nt][kb][lane][8]
#define WS_OW   73728    // 5*4096: [cc][nt][kb][lane][8]
#define WS_EMB  94208    // 301*64 bf16 emb table
#define WS_END  113472
#define WS_BSUM_BYTES (WS_END * 2)

// LDS layout (shorts): weights s0M(4096) + s1..7(7*8192) | bsum | scratch
#define BSOFF   61440
#define HSOFF   62592     // 16 waves x 1024 shorts (2KB each)
#define SLTOT   78976     // 157,952 bytes

typedef __attribute__((ext_vector_type(8))) short  bf16x8;
typedef __attribute__((ext_vector_type(4))) float  f32x4;

#define MFMA __builtin_amdgcn_mfma_f32_16x16x32_bf16

__device__ __forceinline__ unsigned short f2b(float f) {
    union { float f; unsigned int u; } x; x.f = f;
    unsigned int r = x.u + 0x7FFFu + ((x.u >> 16) & 1u);
    return (unsigned short)(r >> 16);
}

__device__ __forceinline__ float sigmoid_fast(float v) {
    return __builtin_amdgcn_rcpf(1.f + __expf(-v));
}

// async global->LDS, 16 B per lane; lds base must be wave-uniform
__device__ __forceinline__ void async16(const unsigned short* g, unsigned short* l) {
    __builtin_amdgcn_global_load_lds(
        (const __attribute__((address_space(1))) unsigned int*)g,
        (__attribute__((address_space(3))) unsigned int*)l, 16, 0, 0);
}

// ---------------- pre-pass: convert + pack (unchanged) ----------------
#define PP_TOTAL (73728 + 20480 + 19264 + 576)

__global__ void prepack(const float* __restrict__ Mw, const float* __restrict__ Ww,
                        const float* __restrict__ outw, const float* __restrict__ emb,
                        const float* __restrict__ Mb, const float* __restrict__ Wb,
                        unsigned short* __restrict__ wsb, float* __restrict__ bsum)
{
    int t = blockIdx.x * 256 + threadIdx.x;
    if (t < 73728) {                       // M+W, step-major 16KB blocks
        int s    = t >> 13;
        int r    = t & 8191;
        int kind = r >> 12;
        int f    = r & 4095;
        int nt   = f >> 10;
        int kb   = (f >> 9) & 1;
        int lane = (f >> 3) & 63;
        int j    = f & 7;
        int nr   = nt * 16 + (lane & 15);
        int k    = kb * 32 + ((lane >> 4) << 3) + j;
        const float* src = kind ? Ww : Mw;
        wsb[WS_MW + t] = f2b(src[(s * DMODEL + nr) * DMODEL + k]);
        return;
    }
    t -= 73728;
    if (t < 20480) {                       // outw fragments
        int j    = t & 7;
        int lane = (t >> 3) & 63;
        int kb   = (t >> 9) & 1;
        int nt   = (t >> 10) & 3;
        int cc   = t >> 12;
        int col  = cc * 64 + nt * 16 + (lane & 15);
        int k    = kb * 32 + ((lane >> 4) << 3) + j;
        float v  = (col < ANUM) ? outw[col * DMODEL + k] : 0.f;
        wsb[WS_OW + t] = f2b(v);
        return;
    }
    t -= 20480;
    if (t < 19264) { wsb[WS_EMB + t] = f2b(emb[t]); return; }
    t -= 19264;
    if (t < 576)   { bsum[t] = Mb[t] + Wb[t]; }
}

// ---------------- main ----------------
__global__ __launch_bounds__(1024, 4)
void carnn_main(const int* __restrict__ acts,
                const unsigned short* __restrict__ wsb,
                const float* __restrict__ bsum,
                const float* __restrict__ outb,
                float* __restrict__ out)
{
    __shared__ __align__(16) unsigned short SL[SLTOT];

    const int tid  = threadIdx.x;
    const int lane = tid & 63;
    const int wv   = tid >> 6;         // 0..15
    const int lrow = lane & 15;        // batch row within wave (B-operand n)
    const int quad = lane >> 4;

    const int brow = (blockIdx.x * 16 + wv) * 16 + lrow;   // global batch row
    const int rowS = brow * SEQ;

    // ---- stage weights s0M + s1..7 (120 chunks of 1KB) ----
    for (int c = wv; c < 120; c += 16) {
        const int goff = (c < 8) ? (c * 512) : ((c + 8) * 512);
        async16(wsb + WS_MW + goff + lane * 8, &SL[c * 512]);
    }
    // ---- stage bsum (2304 B) ----
    {
        const unsigned short* bs = (const unsigned short*)bsum;
        if (wv == 13) async16(bs + lane * 8,         &SL[BSOFF]);
        if (wv == 14) async16(bs + 512 + lane * 8,   &SL[BSOFF + 512]);
        if (wv == 15 && lane < 16)
                      async16(bs + 1024 + lane * 8,  &SL[BSOFF + 1024]);
    }

    // step-0 inputs (overlap with staging)
    const unsigned short* Eb = wsb + WS_EMB;
    int idc = acts[rowS];
    bf16x8 xc0 = *(const bf16x8*)(Eb + idc * DMODEL + quad * 8);
    bf16x8 xc1 = *(const bf16x8*)(Eb + idc * DMODEL + 32 + quad * 8);
    int idn = acts[rowS + 1];

    // per-wave H scratch: 2KB, XOR-swizzled (conflict-free b64 w / b128 r)
    char* const SB = (char*)SL;
    const int swz    = (lrow & 7) << 4;
    const int hbyte  = HSOFF * 2 + wv * 2048 + lrow * 128;
    const int rbyte0 = hbyte + ((quad * 16) ^ swz);          // kb0
    const int rbyte1 = hbyte + ((64 + quad * 16) ^ swz);     // kb1

    __syncthreads();    // the ONLY barrier: weights + bsum staged

    const float* BSf = (const float*)&SL[BSOFF];

    #pragma unroll
    for (int s = 0; s < SEQ; ++s) {
        // prefetch next step's x fragments (id already resident)
        bf16x8 xn0, xn1;
        if (s + 1 < SEQ) {
            xn0 = *(const bf16x8*)(Eb + idn * DMODEL + quad * 8);
            xn1 = *(const bf16x8*)(Eb + idn * DMODEL + 32 + quad * 8);
            if (s + 2 < SEQ) idn = acts[rowS + s + 2];
        }
        // previous-step H fragments (B-operand), wave-private
        bf16x8 h0, h1;
        if (s > 0) {
            h0 = *(const bf16x8*)(SB + rbyte0);
            h1 = *(const bf16x8*)(SB + rbyte1);
        }
        // weight fragment base: LDS for s<8, global (L2) for s8
        const unsigned short* WB;
        if (s == 0)     WB = &SL[0];
        else if (s < 8) WB = &SL[4096 + (s - 1) * 8192];
        else            WB = wsb + WS_MW + 8 * 8192;

        #pragma unroll
        for (int nt = 0; nt < 4; ++nt) {
            const unsigned short* Mf = WB + nt * 1024 + lane * 8;
            bf16x8 am0 = *(const bf16x8*)Mf;
            bf16x8 am1 = *(const bf16x8*)(Mf + 512);
            // acc init = bias vector (feats nt*16+quad*4 .. +3)
            f32x4 acc = *(const f32x4*)(BSf + s * 64 + nt * 16 + quad * 4);
            acc = MFMA(am0, xc0, acc, 0, 0, 0);   // A=weights, B=x (swapped)
            acc = MFMA(am1, xc1, acc, 0, 0, 0);
            if (s > 0) {
                const unsigned short* Wf = WB + 4096 + nt * 1024 + lane * 8;
                bf16x8 aw0 = *(const bf16x8*)Wf;
                bf16x8 aw1 = *(const bf16x8*)(Wf + 512);
                acc = MFMA(aw0, h0, acc, 0, 0, 0);
                acc = MFMA(aw1, h1, acc, 0, 0, 0);
            }
            // sigmoid -> bf16 pack -> one b64 write (4 consecutive feats)
            unsigned int u0 = (unsigned int)f2b(sigmoid_fast(acc[0]))
                            | ((unsigned int)f2b(sigmoid_fast(acc[1])) << 16);
            unsigned int u1 = (unsigned int)f2b(sigmoid_fast(acc[2]))
                            | ((unsigned int)f2b(sigmoid_fast(acc[3])) << 16);
            *(uint2*)(SB + hbyte + ((nt * 32 + quad * 8) ^ swz)) = make_uint2(u0, u1);
        }
        if (s + 1 < SEQ) { xc0 = xn0; xc1 = xn1; }
        // NO barrier -- H is wave-private, lgkmcnt orders write->read
    }

    // ---- projection: A = out_w frags (L2-resident), B = final H ----
    bf16x8 h0 = *(const bf16x8*)(SB + rbyte0);
    bf16x8 h1 = *(const bf16x8*)(SB + rbyte1);
    const unsigned short* OWg = wsb + WS_OW;
    float* orow = out + brow * ANUM;   // lane's batch row

    #pragma unroll
    for (int t = 0; t < 19; ++t) {     // 19 x 16-col tiles cover 304 cols
        const int cc = t >> 2, nt = t & 3;
        const unsigned short* Of = OWg + cc * 4096 + nt * 1024 + lane * 8;
        bf16x8 a0 = *(const bf16x8*)Of;
        bf16x8 a1 = *(const bf16x8*)(Of + 512);
        const int col0 = cc * 64 + nt * 16 + quad * 4;

        f32x4 acc;
        if (col0 < ANUM) acc = *(const f32x4*)(outb + col0);
        else             acc = (f32x4){0.f, 0.f, 0.f, 0.f};
        acc = MFMA(a0, h0, acc, 0, 0, 0);
        acc = MFMA(a1, h1, acc, 0, 0, 0);

        if (col0 < ANUM)               // col0 mult of 4, ANUM=300 mult of 4
            *(f32x4*)(orow + col0) = acc;
    }
}

extern "C" void kernel_launch(void* const* d_in, const int* in_sizes, int n_in,
                              void* d_out, int out_size, void* d_ws, size_t ws_size,
                              hipStream_t stream) {
    const int*   acts = (const int*)  d_in[0];
    const float* emb  = (const float*)d_in[1];
    const float* Mw   = (const float*)d_in[2];
    const float* Mb   = (const float*)d_in[3];
    const float* Ww   = (const float*)d_in[4];
    const float* Wb   = (const float*)d_in[5];
    const float* outw = (const float*)d_in[6];
    const float* outb = (const float*)d_in[7];
    float* out = (float*)d_out;
    (void)in_sizes; (void)n_in; (void)ws_size; (void)out_size;

    unsigned short* wsb = (unsigned short*)d_ws;
    float* bsum = (float*)((char*)d_ws + WS_BSUM_BYTES);

    prepack<<<(PP_TOTAL + 255) / 256, 256, 0, stream>>>(Mw, Ww, outw, emb, Mb, Wb, wsb, bsum);
    carnn_main<<<65536 / 256, 1024, 0, stream>>>(acts, wsb, bsum, outb, out);
}